// Round 2
// baseline (1666.767 us; speedup 1.0000x reference)
//
#include <hip/hip_runtime.h>
#include <cstdint>

typedef unsigned long long ull;

#define N_BOX 8192
#define N_WORDS 128   // 8192 / 64

// ---------------- workspace layout ----------------
// tdiag  : 8192*8  = 65536  B @ 0        (per-candidate intra-word suppressor mask)
// boxes4 : 8192*16 = 131072 B @ 65536
// scores : 8192*4  = 32768  B @ 196608
// rank   : 8192*4  = 32768  B @ 229376
// mask   : 128*8   = 1024   B @ 262144   (valid bitmask, built by k3)
// maxconf: 4 B               @ 263168
#define OFF_TDIAG  0
#define OFF_BOXES  65536
#define OFF_SCORES 196608
#define OFF_RANK   229376
#define OFF_MASK   262144
#define OFF_MAXC   263168

__device__ __forceinline__ ull make_key(float s, int idx) {
    // positive floats: bit pattern is order-preserving. Reversed index in the
    // low 13 bits reproduces stable argsort(-conf): equal conf -> lower index first.
    return (((ull)__float_as_uint(s)) << 13) | (ull)(8191 - idx);
}

__device__ __forceinline__ float box_area(float4 b) {
    return __fmul_rn(__fsub_rn(b.z, b.x), __fsub_rn(b.w, b.y));
}

// exact replica of reference IoU rounding (_rn ops block FMA contraction);
// a = earlier (kept) box, b = later candidate.
__device__ __forceinline__ bool iou_gt_half(float4 a, float aarea, float4 b, float barea) {
    float ix1 = fmaxf(a.x, b.x);
    float iy1 = fmaxf(a.y, b.y);
    float ix2 = fminf(a.z, b.z);
    float iy2 = fminf(a.w, b.w);
    float iw = fmaxf(__fsub_rn(ix2, ix1), 0.0f);
    float ih = fmaxf(__fsub_rn(iy2, iy1), 0.0f);
    float inter = __fmul_rn(iw, ih);
    float uni = __fsub_rn(__fadd_rn(aarea, barea), inter);
    float iou = __fdiv_rn(inter, fmaxf(uni, 1e-9f));
    return iou > 0.5f;
}

// K1: max-reduce conf, zero rank + valid mask
__global__ __launch_bounds__(1024) void k1_max_zero(const float* __restrict__ in,
                                                    float* __restrict__ maxc,
                                                    int* __restrict__ rank,
                                                    ull* __restrict__ mask) {
    int t = threadIdx.x;
    float m = 0.0f;  // conf is uniform [0,1): non-negative
    for (int k = t; k < N_BOX; k += 1024) m = fmaxf(m, in[k * 5 + 4]);
    for (int off = 32; off; off >>= 1) m = fmaxf(m, __shfl_down(m, off));
    __shared__ float wm[16];
    if ((t & 63) == 0) wm[t >> 6] = m;
    __syncthreads();
    if (t == 0) {
        float mm = wm[0];
        for (int k = 1; k < 16; ++k) mm = fmaxf(mm, wm[k]);
        *maxc = mm;
    }
    for (int k = t; k < N_BOX; k += 1024) rank[k] = 0;
    if (t < N_WORDS) mask[t] = 0ull;
}

// K2: rank[i] = #{ j : key_j > key_i }  (descending sort position, stable ties)
__global__ __launch_bounds__(256) void k2_rank(const float* __restrict__ in,
                                               const float* __restrict__ maxc_p,
                                               int* __restrict__ rank) {
    __shared__ ull keys[1024];
    int t = threadIdx.x;
    int bx = blockIdx.x;
    int it = bx & 31;       // i tile: 256 boxes
    int jt = bx >> 5;       // j tile: 1024 boxes (8 tiles)
    float maxc = *maxc_p;
    for (int r = 0; r < 4; ++r) {
        int j = jt * 1024 + r * 256 + t;
        float s = __fdiv_rn(in[j * 5 + 4], maxc);
        keys[r * 256 + t] = make_key(s, j);
    }
    __syncthreads();
    int i = it * 256 + t;
    ull ki = make_key(__fdiv_rn(in[i * 5 + 4], maxc), i);
    int cnt = 0;
    #pragma unroll 8
    for (int k = 0; k < 1024; ++k) cnt += (keys[k] > ki) ? 1 : 0;
    atomicAdd(&rank[i], cnt);
}

// K3: scatter boxes/scores into sorted order, build valid bitmask
__global__ __launch_bounds__(256) void k3_scatter(const float* __restrict__ in,
                                                  const int* __restrict__ rank,
                                                  const float* __restrict__ maxc_p,
                                                  float4* __restrict__ boxes4,
                                                  float* __restrict__ scores,
                                                  ull* __restrict__ mask) {
    int i = blockIdx.x * 256 + threadIdx.x;
    float cx = in[i * 5 + 0];
    float cy = in[i * 5 + 1];
    float w  = in[i * 5 + 2];
    float h  = in[i * 5 + 3];
    float c  = in[i * 5 + 4];
    float maxc = *maxc_p;
    float s = __fdiv_rn(c, maxc);
    int r = rank[i];
    float4 b;
    b.x = __fsub_rn(cx, __fmul_rn(w, 0.5f));
    b.y = __fsub_rn(cy, __fmul_rn(h, 0.5f));
    b.z = __fadd_rn(cx, __fmul_rn(w, 0.5f));
    b.w = __fadd_rn(cy, __fmul_rn(h, 0.5f));
    boxes4[r] = b;
    scores[r] = s;
    if (s >= 0.5f) atomicOr(&mask[r >> 6], 1ull << (r & 63));
}

// K4b: transposed intra-word suppressor table.
// tdiag[w*64 + l] = { bits a<l : iou(box[w*64+a], box[w*64+l]) > 0.5 }
__global__ __launch_bounds__(64) void k4b_tdiag(const float4* __restrict__ boxes4,
                                                ull* __restrict__ tdiag) {
    __shared__ float4 sb[64];
    __shared__ float sa[64];
    int wb = blockIdx.x;
    int l = threadIdx.x;
    float4 me = boxes4[wb * 64 + l];
    sb[l] = me;
    sa[l] = box_area(me);
    __syncthreads();
    float myarea = sa[l];
    ull bits = 0;
    for (int a = 0; a < 64; ++a) {
        if (a >= l) break;
        if (iou_gt_half(sb[a], sa[a], me, myarea)) bits |= 1ull << a;
    }
    tdiag[wb * 64 + l] = bits;
}

// K5: block-sequential greedy NMS. One 1024-thread block; alive mask in 1KB LDS;
// serial chain contains NO global-memory round trips (tdiag prefetched 1 step ahead,
// IoU-on-the-fly for cross-word suppression). Writes final output.
__global__ __launch_bounds__(1024) void k5_nms(const float4* __restrict__ boxes4,
                                               const float* __restrict__ scores,
                                               const ull* __restrict__ gmask,
                                               const ull* __restrict__ tdiag,
                                               float* __restrict__ out) {
    __shared__ unsigned amask32[2 * N_WORDS];   // alive mask, u32 halves of u64 words
    int t = threadIdx.x;
    int lane = t & 63;
    int wave = t >> 6;
    int wmy = t >> 3;            // word this thread applies suppression to
    int bsh = (t & 7) * 8;       // bit offset of my byte within that word
    int j0 = t * 8;              // my 8 owned candidates

    if (t < 2 * N_WORDS) amask32[t] = ((const unsigned*)gmask)[t];

    // own 8 boxes + areas in registers
    float4 mb[8];
    float marea[8];
    #pragma unroll
    for (int r = 0; r < 8; ++r) {
        mb[r] = boxes4[j0 + r];
        marea[r] = box_area(mb[r]);
    }

    ull tdg_cur = 0, tdg_next = 0;
    if (wave == 0) tdg_cur = tdiag[lane];   // word 0
    __syncthreads();

    for (int wb = 0; wb < N_WORDS; ++wb) {
        ull aw = (ull)amask32[2 * wb] | ((ull)amask32[2 * wb + 1] << 32);
        if (wave == 0 && wb + 1 < N_WORDS) tdg_next = tdiag[(wb + 1) * 64 + lane];
        if (aw == 0) { tdg_cur = tdg_next; continue; }   // uniform skip

        if (wave == 0) {
            // intra-word greedy resolve: confirm/kill fixpoint (>=1 decided per round)
            ull td = tdg_cur;
            ull alive = aw, kept = 0;
            while (alive & ~kept) {
                bool al = (alive >> lane) & 1;
                bool kp = (kept >> lane) & 1;
                bool nosup = (td & alive) == 0;   // no alive suppressor below me
                bool supk  = (td & kept) != 0;    // a kept one suppresses me
                ull nk = __ballot(al && !kp && nosup);
                ull nd = __ballot(al && supk);
                kept |= nk;
                alive &= ~nd;
            }
            if (lane == 0) {
                amask32[2 * wb]     = (unsigned)kept;
                amask32[2 * wb + 1] = (unsigned)(kept >> 32);
            }
        }
        tdg_cur = tdg_next;
        __syncthreads();

        ull kw = (ull)amask32[2 * wb] | ((ull)amask32[2 * wb + 1] << 32);
        if (kw && wmy > wb) {
            unsigned b8 = (amask32[2 * wmy + (bsh >> 5)] >> (bsh & 31)) & 0xffu;
            if (b8) {
                unsigned sup8 = 0;
                ull kk = kw;
                while (kk) {
                    int ib = __builtin_ctzll(kk);
                    kk &= kk - 1;
                    float4 bi = boxes4[wb * 64 + ib];   // wave-uniform -> L1/L2 broadcast
                    float ia = box_area(bi);
                    unsigned bb = b8;
                    while (bb) {
                        int jb = __builtin_ctz(bb);
                        bb &= bb - 1;
                        if (iou_gt_half(bi, ia, mb[jb], marea[jb])) sup8 |= 1u << jb;
                    }
                }
                sup8 &= b8;
                if (sup8) atomicAnd(&amask32[2 * wmy + (bsh >> 5)], ~(sup8 << (bsh & 31)));
            }
        }
        __syncthreads();
    }

    // epilogue: write all 8192 output rows (zeroed where not kept)
    #pragma unroll
    for (int r = 0; r < 8; ++r) {
        int j = j0 + r;
        bool keptb = (amask32[j >> 5] >> (j & 31)) & 1u;
        float4 b = mb[r];
        float s = scores[j];
        out[j * 5 + 0] = keptb ? b.x : 0.0f;
        out[j * 5 + 1] = keptb ? b.y : 0.0f;
        out[j * 5 + 2] = keptb ? b.z : 0.0f;
        out[j * 5 + 3] = keptb ? b.w : 0.0f;
        out[j * 5 + 4] = keptb ? s   : 0.0f;
    }
}

extern "C" void kernel_launch(void* const* d_in, const int* in_sizes, int n_in,
                              void* d_out, int out_size, void* d_ws, size_t ws_size,
                              hipStream_t stream) {
    const float* in = (const float*)d_in[0];
    char* ws = (char*)d_ws;
    ull* tdiag     = (ull*)(ws + OFF_TDIAG);
    float4* boxes4 = (float4*)(ws + OFF_BOXES);
    float* scores  = (float*)(ws + OFF_SCORES);
    int* rank      = (int*)(ws + OFF_RANK);
    ull* mask      = (ull*)(ws + OFF_MASK);
    float* maxc    = (float*)(ws + OFF_MAXC);
    float* out     = (float*)d_out;

    k1_max_zero<<<1, 1024, 0, stream>>>(in, maxc, rank, mask);
    k2_rank<<<256, 256, 0, stream>>>(in, maxc, rank);
    k3_scatter<<<32, 256, 0, stream>>>(in, rank, maxc, boxes4, scores, mask);
    k4b_tdiag<<<N_WORDS, 64, 0, stream>>>(boxes4, tdiag);
    k5_nms<<<1, 1024, 0, stream>>>(boxes4, scores, mask, tdiag, out);
}

// Round 3
// 409.029 us; speedup vs baseline: 4.0749x; 4.0749x over previous
//
#include <hip/hip_runtime.h>
#include <cstdint>

typedef unsigned long long ull;

#define N_BOX 8192
#define N_WORDS 128   // 8192 / 64
#define CH 512        // chunk size
#define WPC 8         // words per chunk
#define NCH 16        // chunks

// ---------------- workspace layout ----------------
// TB (triangular transposed col-blocks): 61440 rows * 64 B = 3,932,160 @ 0
// D  (diagonal blocks): 16*512*8*8 = 524,288 B @ 3,932,160
// boxes4 : 131072 B @ 4,456,448
// scores : 32768  B @ 4,587,520
// rank   : 32768  B @ 4,620,288
// mask   : 1024   B @ 4,653,056
// maxconf: 4 B      @ 4,654,080
#define OFF_TB     0
#define OFF_D      3932160
#define OFF_BOXES  4456448
#define OFF_SCORES 4587520
#define OFF_RANK   4620288
#define OFF_MASK   4653056
#define OFF_MAXC   4654080

// rows before chunk c in TB = sum_{c'<c} (8192 - 512*(c'+1))
__device__ __forceinline__ int rows_before(int c) {
    return 8192 * c - 256 * c * (c + 1);
}

__device__ __forceinline__ ull make_key(float s, int idx) {
    // positive floats: bit pattern is order-preserving. Reversed index in the
    // low 13 bits reproduces stable argsort(-conf): equal conf -> lower index first.
    return (((ull)__float_as_uint(s)) << 13) | (ull)(8191 - idx);
}

__device__ __forceinline__ float box_area(float4 b) {
    return __fmul_rn(__fsub_rn(b.z, b.x), __fsub_rn(b.w, b.y));
}

// exact replica of reference IoU rounding (_rn ops block FMA contraction); symmetric.
__device__ __forceinline__ bool iou_gt_half(float4 a, float aarea, float4 b, float barea) {
    float ix1 = fmaxf(a.x, b.x);
    float iy1 = fmaxf(a.y, b.y);
    float ix2 = fminf(a.z, b.z);
    float iy2 = fminf(a.w, b.w);
    float iw = fmaxf(__fsub_rn(ix2, ix1), 0.0f);
    float ih = fmaxf(__fsub_rn(iy2, iy1), 0.0f);
    float inter = __fmul_rn(iw, ih);
    float uni = __fsub_rn(__fadd_rn(aarea, barea), inter);
    float iou = __fdiv_rn(inter, fmaxf(uni, 1e-9f));
    return iou > 0.5f;
}

// K1: max-reduce conf, zero rank + valid mask
__global__ __launch_bounds__(1024) void k1_max_zero(const float* __restrict__ in,
                                                    float* __restrict__ maxc,
                                                    int* __restrict__ rank,
                                                    ull* __restrict__ mask) {
    int t = threadIdx.x;
    float m = 0.0f;  // conf is uniform [0,1): non-negative
    for (int k = t; k < N_BOX; k += 1024) m = fmaxf(m, in[k * 5 + 4]);
    for (int off = 32; off; off >>= 1) m = fmaxf(m, __shfl_down(m, off));
    __shared__ float wm[16];
    if ((t & 63) == 0) wm[t >> 6] = m;
    __syncthreads();
    if (t == 0) {
        float mm = wm[0];
        for (int k = 1; k < 16; ++k) mm = fmaxf(mm, wm[k]);
        *maxc = mm;
    }
    for (int k = t; k < N_BOX; k += 1024) rank[k] = 0;
    if (t < N_WORDS) mask[t] = 0ull;
}

// K2: rank[i] = #{ j : key_j > key_i }  (descending sort position, stable ties)
__global__ __launch_bounds__(256) void k2_rank(const float* __restrict__ in,
                                               const float* __restrict__ maxc_p,
                                               int* __restrict__ rank) {
    __shared__ ull keys[1024];
    int t = threadIdx.x;
    int bx = blockIdx.x;
    int it = bx & 31;       // i tile: 256 boxes
    int jt = bx >> 5;       // j tile: 1024 boxes (8 tiles)
    float maxc = *maxc_p;
    for (int r = 0; r < 4; ++r) {
        int j = jt * 1024 + r * 256 + t;
        float s = __fdiv_rn(in[j * 5 + 4], maxc);
        keys[r * 256 + t] = make_key(s, j);
    }
    __syncthreads();
    int i = it * 256 + t;
    ull ki = make_key(__fdiv_rn(in[i * 5 + 4], maxc), i);
    int cnt = 0;
    #pragma unroll 8
    for (int k = 0; k < 1024; ++k) cnt += (keys[k] > ki) ? 1 : 0;
    atomicAdd(&rank[i], cnt);
}

// K3: scatter boxes/scores into sorted order, build valid bitmask
__global__ __launch_bounds__(256) void k3_scatter(const float* __restrict__ in,
                                                  const int* __restrict__ rank,
                                                  const float* __restrict__ maxc_p,
                                                  float4* __restrict__ boxes4,
                                                  float* __restrict__ scores,
                                                  ull* __restrict__ mask) {
    int i = blockIdx.x * 256 + threadIdx.x;
    float cx = in[i * 5 + 0];
    float cy = in[i * 5 + 1];
    float w  = in[i * 5 + 2];
    float h  = in[i * 5 + 3];
    float c  = in[i * 5 + 4];
    float maxc = *maxc_p;
    float s = __fdiv_rn(c, maxc);
    int r = rank[i];
    float4 b;
    b.x = __fsub_rn(cx, __fmul_rn(w, 0.5f));
    b.y = __fsub_rn(cy, __fmul_rn(h, 0.5f));
    b.z = __fadd_rn(cx, __fmul_rn(w, 0.5f));
    b.w = __fadd_rn(cy, __fmul_rn(h, 0.5f));
    boxes4[r] = b;
    scores[r] = s;
    if (s >= 0.5f) atomicOr(&mask[r >> 6], 1ull << (r & 63));
}

// K4: build suppression bit tables.
//  blockIdx.x < 30 : TB col-block — for j-tile of chunk c, row TB[c][j] = 8 words of
//                    suppressor bits from chunk c (all i in chunk < j guaranteed).
//  blockIdx.x == 30: D diagonal block of chunk c, rows pre-masked jl > kl.
// Score-gated skips are provably never read (kept_c==0, or j never alive).
__global__ __launch_bounds__(256) void k4_build(const float4* __restrict__ boxes4,
                                                const float* __restrict__ scores,
                                                ull* __restrict__ TB,
                                                ull* __restrict__ D) {
    int c = blockIdx.y;
    int t = threadIdx.x;
    if (scores[c * CH] < 0.5f) return;   // chunk invalid -> never a suppressor source

    __shared__ float4 sb[CH];
    __shared__ float sa[CH];

    if (blockIdx.x == 30) {
        for (int i = t; i < CH; i += 256) {
            float4 b = boxes4[c * CH + i];
            sb[i] = b;
            sa[i] = box_area(b);
        }
        __syncthreads();
        #pragma unroll
        for (int rr = 0; rr < 2; ++rr) {
            int kl = t + rr * 256;
            float4 bk = sb[kl];
            float ak = sa[kl];
            ull* drow = D + ((size_t)(c * CH + kl)) * WPC;
            for (int w = 0; w < WPC; ++w) {
                ull bits = 0;
                for (int kk = 0; kk < 64; ++kk) {
                    int jl = w * 64 + kk;
                    if (jl > kl && iou_gt_half(bk, ak, sb[jl], sa[jl])) bits |= 1ull << kk;
                }
                drow[w] = bits;
            }
        }
    } else {
        int j0 = CH * (c + 1) + blockIdx.x * 256;
        if (j0 >= N_BOX) return;
        if (scores[j0] < 0.5f) return;   // whole j-tile invalid (scores sorted desc)
        for (int i = t; i < CH; i += 256) {
            float4 b = boxes4[c * CH + i];
            sb[i] = b;
            sa[i] = box_area(b);
        }
        __syncthreads();
        int j = j0 + t;
        float4 bj = boxes4[j];
        float aj = box_area(bj);
        ull* row = TB + ((size_t)(rows_before(c) + (j - CH * (c + 1)))) * WPC;
        for (int w = 0; w < WPC; ++w) {
            ull bits = 0;
            for (int kk = 0; kk < 64; ++kk) {
                if (iou_gt_half(sb[w * 64 + kk], sa[w * 64 + kk], bj, aj)) bits |= 1ull << kk;
            }
            row[w] = bits;
        }
    }
}

// K5: chunk-sequential greedy NMS, one 1024-thread block.
// Wave 0: serial scan of chunk c from LDS (per kept step: 1x ds_read_b64 + AND + shfl).
// Waves 1-15: prefetch next chunk's D block (double-buffered).
// All: apply kept_c to later alive boxes via precomputed TB (8-word AND).
__global__ __launch_bounds__(1024) void k5_nms(const float4* __restrict__ boxes4,
                                               const float* __restrict__ scores,
                                               const ull* __restrict__ gmask,
                                               const ull* __restrict__ TB,
                                               const ull* __restrict__ Dg,
                                               float* __restrict__ out) {
    __shared__ ull Dbuf[2][CH * WPC];        // 2 x 32 KB
    __shared__ unsigned amask32[2 * N_WORDS];
    __shared__ ull keptw[WPC];
    int t = threadIdx.x;
    int lane = t & 63;
    int wave = t >> 6;

    if (t < 2 * N_WORDS) amask32[t] = ((const unsigned*)gmask)[t];
    for (int i = t; i < CH * WPC; i += 1024) Dbuf[0][i] = Dg[i];   // chunk 0 diag
    __syncthreads();

    int cur = 0;
    for (int c = 0; c < NCH; ++c) {
        if (wave == 0) {
            // ---- serial greedy scan of chunk c (alive words in lanes 0..7) ----
            ull al = 0;
            if (lane < WPC)
                al = (ull)amask32[c * 16 + 2 * lane] |
                     ((ull)amask32[c * 16 + 2 * lane + 1] << 32);
            const ull* Dc = Dbuf[cur];
            for (int w = 0; w < WPC; ++w) {
                ull word = __shfl(al, w);
                while (word) {
                    int b = __builtin_ctzll(word);          // candidate k is KEPT
                    ull row = (lane < WPC) ? Dc[((w << 6) + b) * WPC + lane] : 0ull;
                    al &= ~row;                             // row pre-masked jl > kl
                    if (b == 63) break;
                    word = __shfl(al, w) & (~0ull << (b + 1));
                }
            }
            if (lane < WPC) {
                amask32[c * 16 + 2 * lane]     = (unsigned)al;   // final al == kept_c
                amask32[c * 16 + 2 * lane + 1] = (unsigned)(al >> 32);
                keptw[lane] = al;
            }
        } else if (c + 1 < NCH) {
            // ---- prefetch next chunk's D block into the other buffer ----
            int base = (c + 1) * CH * WPC;
            for (int i = t - 64; i < CH * WPC; i += 960) Dbuf[cur ^ 1][i] = Dg[base + i];
        }
        __syncthreads();

        // ---- phase b: apply kept_c to all later alive boxes via TB ----
        ull anyk = keptw[0] | keptw[1] | keptw[2] | keptw[3] |
                   keptw[4] | keptw[5] | keptw[6] | keptw[7];
        if (anyk) {
            ull kw[WPC];
            #pragma unroll
            for (int k = 0; k < WPC; ++k) kw[k] = keptw[k];
            const ull* TBc = TB + (size_t)rows_before(c) * WPC;
            int jbase = CH * (c + 1);
            for (int j = jbase + t; j < N_BOX; j += 1024) {
                if ((amask32[j >> 5] >> (j & 31)) & 1u) {
                    const ull* r = TBc + (size_t)(j - jbase) * WPC;
                    ull acc = 0;
                    #pragma unroll
                    for (int k = 0; k < WPC; ++k) acc |= r[k] & kw[k];
                    if (acc) atomicAnd(&amask32[j >> 5], ~(1u << (j & 31)));
                }
            }
        }
        cur ^= 1;
        __syncthreads();
    }

    // ---- epilogue: write all 8192 output rows ----
    #pragma unroll
    for (int rr = 0; rr < 8; ++rr) {
        int j = t * 8 + rr;
        bool kept = (amask32[j >> 5] >> (j & 31)) & 1u;
        float4 b = boxes4[j];
        float s = scores[j];
        out[j * 5 + 0] = kept ? b.x : 0.0f;
        out[j * 5 + 1] = kept ? b.y : 0.0f;
        out[j * 5 + 2] = kept ? b.z : 0.0f;
        out[j * 5 + 3] = kept ? b.w : 0.0f;
        out[j * 5 + 4] = kept ? s   : 0.0f;
    }
}

extern "C" void kernel_launch(void* const* d_in, const int* in_sizes, int n_in,
                              void* d_out, int out_size, void* d_ws, size_t ws_size,
                              hipStream_t stream) {
    const float* in = (const float*)d_in[0];
    char* ws = (char*)d_ws;
    ull* TB        = (ull*)(ws + OFF_TB);
    ull* D         = (ull*)(ws + OFF_D);
    float4* boxes4 = (float4*)(ws + OFF_BOXES);
    float* scores  = (float*)(ws + OFF_SCORES);
    int* rank      = (int*)(ws + OFF_RANK);
    ull* mask      = (ull*)(ws + OFF_MASK);
    float* maxc    = (float*)(ws + OFF_MAXC);
    float* out     = (float*)d_out;

    k1_max_zero<<<1, 1024, 0, stream>>>(in, maxc, rank, mask);
    k2_rank<<<256, 256, 0, stream>>>(in, maxc, rank);
    k3_scatter<<<32, 256, 0, stream>>>(in, rank, maxc, boxes4, scores, mask);
    k4_build<<<dim3(31, 16), 256, 0, stream>>>(boxes4, scores, TB, D);
    k5_nms<<<1, 1024, 0, stream>>>(boxes4, scores, mask, TB, D, out);
}

// Round 4
// 144.660 us; speedup vs baseline: 11.5219x; 2.8275x over previous
//
#include <hip/hip_runtime.h>
#include <cstdint>

typedef unsigned long long ull;

#define N_BOX 8192
#define N_WORDS 128   // 8192 / 64
#define CH 512        // chunk size
#define WPC 8         // words per chunk
#define NCH 16        // chunks

// ---------------- workspace layout ----------------
// TB (triangular transposed col-blocks): 61440 rows * 64 B = 3,932,160 @ 0
// TD (per-chunk transposed tables):      16 * 32 KB        =   524,288 @ 3,932,160
// boxes4 : 131072 B @ 4,456,448
// scores : 32768  B @ 4,587,520
// rank   : 32768  B @ 4,620,288
// mask   : 1024   B @ 4,653,056
// maxconf: 4 B      @ 4,654,080
// vb     : 4 B      @ 4,654,084
#define OFF_TB     0
#define OFF_TD     3932160
#define OFF_BOXES  4456448
#define OFF_SCORES 4587520
#define OFF_RANK   4620288
#define OFF_MASK   4653056
#define OFF_MAXC   4654080
#define OFF_VB     4654084

// rows before chunk c in TB = sum_{c'<c} (8192 - 512*(c'+1))
__device__ __forceinline__ int rows_before(int c) {
    return 8192 * c - 256 * c * (c + 1);
}

__device__ __forceinline__ ull make_key(float s, int idx) {
    // positive floats: bit pattern is order-preserving. Reversed index in the
    // low 13 bits reproduces stable argsort(-conf): equal conf -> lower index first.
    return (((ull)__float_as_uint(s)) << 13) | (ull)(8191 - idx);
}

__device__ __forceinline__ float box_area(float4 b) {
    return __fmul_rn(__fsub_rn(b.z, b.x), __fsub_rn(b.w, b.y));
}

// exact replica of reference IoU rounding (_rn ops block FMA contraction); symmetric.
__device__ __forceinline__ bool iou_gt_half(float4 a, float aarea, float4 b, float barea) {
    float ix1 = fmaxf(a.x, b.x);
    float iy1 = fmaxf(a.y, b.y);
    float ix2 = fminf(a.z, b.z);
    float iy2 = fminf(a.w, b.w);
    float iw = fmaxf(__fsub_rn(ix2, ix1), 0.0f);
    float ih = fmaxf(__fsub_rn(iy2, iy1), 0.0f);
    float inter = __fmul_rn(iw, ih);
    float uni = __fsub_rn(__fadd_rn(aarea, barea), inter);
    float iou = __fdiv_rn(inter, fmaxf(uni, 1e-9f));
    return iou > 0.5f;
}

// K1: max-reduce conf, zero rank + valid mask + vb counter
__global__ __launch_bounds__(1024) void k1_max_zero(const float* __restrict__ in,
                                                    float* __restrict__ maxc,
                                                    int* __restrict__ rank,
                                                    ull* __restrict__ mask,
                                                    int* __restrict__ vbp) {
    int t = threadIdx.x;
    float m = 0.0f;  // conf is uniform [0,1): non-negative
    for (int k = t; k < N_BOX; k += 1024) m = fmaxf(m, in[k * 5 + 4]);
    for (int off = 32; off; off >>= 1) m = fmaxf(m, __shfl_down(m, off));
    __shared__ float wm[16];
    if ((t & 63) == 0) wm[t >> 6] = m;
    __syncthreads();
    if (t == 0) {
        float mm = wm[0];
        for (int k = 1; k < 16; ++k) mm = fmaxf(mm, wm[k]);
        *maxc = mm;
        *vbp = 0;
    }
    for (int k = t; k < N_BOX; k += 1024) rank[k] = 0;
    if (t < N_WORDS) mask[t] = 0ull;
}

// K2: rank[i] = #{ j : key_j > key_i }  (descending sort position, stable ties)
__global__ __launch_bounds__(256) void k2_rank(const float* __restrict__ in,
                                               const float* __restrict__ maxc_p,
                                               int* __restrict__ rank) {
    __shared__ ull keys[1024];
    int t = threadIdx.x;
    int bx = blockIdx.x;
    int it = bx & 31;       // i tile: 256 boxes
    int jt = bx >> 5;       // j tile: 1024 boxes (8 tiles)
    float maxc = *maxc_p;
    for (int r = 0; r < 4; ++r) {
        int j = jt * 1024 + r * 256 + t;
        float s = __fdiv_rn(in[j * 5 + 4], maxc);
        keys[r * 256 + t] = make_key(s, j);
    }
    __syncthreads();
    int i = it * 256 + t;
    ull ki = make_key(__fdiv_rn(in[i * 5 + 4], maxc), i);
    int cnt = 0;
    #pragma unroll 8
    for (int k = 0; k < 1024; ++k) cnt += (keys[k] > ki) ? 1 : 0;
    atomicAdd(&rank[i], cnt);
}

// K3: scatter boxes/scores into sorted order, build valid bitmask + count
__global__ __launch_bounds__(256) void k3_scatter(const float* __restrict__ in,
                                                  const int* __restrict__ rank,
                                                  const float* __restrict__ maxc_p,
                                                  float4* __restrict__ boxes4,
                                                  float* __restrict__ scores,
                                                  ull* __restrict__ mask,
                                                  int* __restrict__ vbp) {
    int i = blockIdx.x * 256 + threadIdx.x;
    float cx = in[i * 5 + 0];
    float cy = in[i * 5 + 1];
    float w  = in[i * 5 + 2];
    float h  = in[i * 5 + 3];
    float c  = in[i * 5 + 4];
    float maxc = *maxc_p;
    float s = __fdiv_rn(c, maxc);
    int r = rank[i];
    float4 b;
    b.x = __fsub_rn(cx, __fmul_rn(w, 0.5f));
    b.y = __fsub_rn(cy, __fmul_rn(h, 0.5f));
    b.z = __fadd_rn(cx, __fmul_rn(w, 0.5f));
    b.w = __fadd_rn(cy, __fmul_rn(h, 0.5f));
    boxes4[r] = b;
    scores[r] = s;
    if (s >= 0.5f) {
        atomicOr(&mask[r >> 6], 1ull << (r & 63));
        atomicAdd(vbp, 1);
    }
}

// K4: build suppression bit tables (TB cross-chunk rows + TD per-chunk transposed).
//  bid <  1920 : TB — 32 j-rows x 8 words for (chunk c, j-tile)
//  bid >= 1920 : TD — TD[c][w][jl] = mask of word-w chunk boxes suppressing jl
//                (w == jl's word: only intra-word bits a < jl&63; w > word: 0/unused)
__global__ __launch_bounds__(256) void k4_build(const float4* __restrict__ boxes4,
                                                const float* __restrict__ scores,
                                                ull* __restrict__ TB,
                                                ull* __restrict__ TD) {
    __shared__ float4 sb[CH];
    __shared__ float sa[CH];
    int bid = blockIdx.x;
    int t = threadIdx.x;
    int c, j0;
    bool diag;
    if (bid >= 1920) {
        diag = true;
        int d = bid - 1920;
        c = d >> 4;
        j0 = (d & 15) * 32;                     // local jl tile
    } else {
        diag = false;
        c = 0;
        int rem = bid;
        while (rem >= 240 - 16 * c) { rem -= 240 - 16 * c; ++c; }
        j0 = CH * (c + 1) + rem * 32;           // global j tile
    }
    if (scores[c * CH] < 0.5f) return;          // chunk never a suppressor source
    if (!diag && scores[j0] < 0.5f) return;     // whole j-tile never alive

    for (int i = t; i < CH; i += 256) {
        float4 b = boxes4[c * CH + i];
        sb[i] = b;
        sa[i] = box_area(b);
    }
    __syncthreads();

    int w = t & 7;
    int jj = j0 + (t >> 3);
    if (diag) {
        int jl = jj;                            // 0..511
        float4 me = sb[jl];
        float ma = sa[jl];
        int wj = jl >> 6;
        int lim = (w < wj) ? 64 : ((w == wj) ? (jl & 63) : 0);
        ull bits = 0;
        for (int k = 0; k < lim; ++k)
            if (iou_gt_half(sb[w * 64 + k], sa[w * 64 + k], me, ma)) bits |= 1ull << k;
        TD[c * 4096 + w * 512 + jl] = bits;
    } else {
        int j = jj;
        float4 me = boxes4[j];
        float ma = box_area(me);
        ull bits = 0;
        for (int k = 0; k < 64; ++k)
            if (iou_gt_half(sb[w * 64 + k], sa[w * 64 + k], me, ma)) bits |= 1ull << k;
        TB[(size_t)(rows_before(c) + (j - CH * (c + 1))) * WPC + w] = bits;
    }
}

// K5: chunk-sequential greedy NMS, one 1024-thread block.
// Wave 0 scans chunk c from LDS: per word = 1 ds_read_b64 (td) + ballot fixpoint
// (VALU/SALU only) + up-to-7 ds_read_b64 applies. No shfl, no global on serial path.
// Waves 1-15 prefetch next chunk's TD (double-buffered).
// Phase b: all waves apply kept_c to later alive boxes via TB (8-word AND).
__global__ __launch_bounds__(1024) void k5_nms(const float4* __restrict__ boxes4,
                                               const float* __restrict__ scores,
                                               const ull* __restrict__ gmask,
                                               const ull* __restrict__ TBg,
                                               const ull* __restrict__ TDg,
                                               const int* __restrict__ vbp,
                                               float* __restrict__ out) {
    __shared__ ull TDb[2][CH * WPC];            // 2 x 32 KB
    __shared__ unsigned amask32[2 * N_WORDS];
    __shared__ ull keptw[WPC];
    __shared__ int svb;
    int t = threadIdx.x;
    int lane = t & 63;
    int wave = t >> 6;

    if (t < 2 * N_WORDS) amask32[t] = ((const unsigned*)gmask)[t];
    if (t == 0) svb = *vbp;
    if (t < WPC) keptw[t] = 0;
    for (int i = t; i < CH * WPC; i += 1024) TDb[0][i] = TDg[i];   // chunk 0
    __syncthreads();

    int vb = svb;
    int nchv = (vb + CH - 1) / CH;
    int cur = 0;
    for (int c = 0; c < nchv; ++c) {
        if (wave == 0) {
            const ull* T = TDb[cur];
            ull alive[WPC];
            #pragma unroll
            for (int w = 0; w < WPC; ++w)
                alive[w] = (ull)amask32[c * 16 + 2 * w] |
                           ((ull)amask32[c * 16 + 2 * w + 1] << 32);
            #pragma unroll
            for (int w = 0; w < WPC; ++w) {
                ull word = alive[w];
                if (!word) continue;
                ull td = T[w * 512 + w * 64 + lane];   // intra-word suppressors of my lane
                // ballot fixpoint: lowest undecided bit decided every round
                ull a2 = word, kept = 0;
                while (a2 & ~kept) {
                    bool al = (a2 >> lane) & 1;
                    bool kp = (kept >> lane) & 1;
                    ull nk = __ballot(al && !kp && ((td & a2) == 0));
                    ull nd = __ballot(al && !kp && ((td & kept) != 0));
                    kept |= nk;
                    a2 &= ~nd;
                }
                alive[w] = kept;
                // apply kept to later words of this chunk
                #pragma unroll
                for (int j = 0; j < WPC; ++j) {
                    if (j <= w) continue;
                    if (!alive[j]) continue;
                    ull m = T[w * 512 + j * 64 + lane];  // word-w suppressors of (j,lane)
                    alive[j] &= ~__ballot((m & kept) != 0);
                }
            }
            if (lane == 0) {
                #pragma unroll
                for (int w = 0; w < WPC; ++w) {
                    amask32[c * 16 + 2 * w]     = (unsigned)alive[w];
                    amask32[c * 16 + 2 * w + 1] = (unsigned)(alive[w] >> 32);
                    keptw[w] = alive[w];
                }
            }
        } else if (c + 1 < nchv) {
            int base = (c + 1) * CH * WPC;
            for (int i = t - 64; i < CH * WPC; i += 960) TDb[cur ^ 1][i] = TDg[base + i];
        }
        __syncthreads();

        ull kw[WPC];
        ull anyk = 0;
        #pragma unroll
        for (int k = 0; k < WPC; ++k) { kw[k] = keptw[k]; anyk |= kw[k]; }
        if (anyk) {
            const ull* TBc = TBg + (size_t)rows_before(c) * WPC;
            int jbase = CH * (c + 1);
            for (int j = jbase + t; j < vb; j += 1024) {
                if ((amask32[j >> 5] >> (j & 31)) & 1u) {
                    const ull* r = TBc + (size_t)(j - jbase) * WPC;
                    ull acc = 0;
                    #pragma unroll
                    for (int k = 0; k < WPC; ++k) acc |= r[k] & kw[k];
                    if (acc) atomicAnd(&amask32[j >> 5], ~(1u << (j & 31)));
                }
            }
        }
        cur ^= 1;
        __syncthreads();
    }

    // ---- epilogue: write all 8192 output rows ----
    #pragma unroll
    for (int rr = 0; rr < 8; ++rr) {
        int j = t * 8 + rr;
        bool kept = (amask32[j >> 5] >> (j & 31)) & 1u;
        float4 b = boxes4[j];
        float s = scores[j];
        out[j * 5 + 0] = kept ? b.x : 0.0f;
        out[j * 5 + 1] = kept ? b.y : 0.0f;
        out[j * 5 + 2] = kept ? b.z : 0.0f;
        out[j * 5 + 3] = kept ? b.w : 0.0f;
        out[j * 5 + 4] = kept ? s   : 0.0f;
    }
}

extern "C" void kernel_launch(void* const* d_in, const int* in_sizes, int n_in,
                              void* d_out, int out_size, void* d_ws, size_t ws_size,
                              hipStream_t stream) {
    const float* in = (const float*)d_in[0];
    char* ws = (char*)d_ws;
    ull* TB        = (ull*)(ws + OFF_TB);
    ull* TD        = (ull*)(ws + OFF_TD);
    float4* boxes4 = (float4*)(ws + OFF_BOXES);
    float* scores  = (float*)(ws + OFF_SCORES);
    int* rank      = (int*)(ws + OFF_RANK);
    ull* mask      = (ull*)(ws + OFF_MASK);
    float* maxc    = (float*)(ws + OFF_MAXC);
    int* vbp       = (int*)(ws + OFF_VB);
    float* out     = (float*)d_out;

    k1_max_zero<<<1, 1024, 0, stream>>>(in, maxc, rank, mask, vbp);
    k2_rank<<<256, 256, 0, stream>>>(in, maxc, rank);
    k3_scatter<<<32, 256, 0, stream>>>(in, rank, maxc, boxes4, scores, mask, vbp);
    k4_build<<<2176, 256, 0, stream>>>(boxes4, scores, TB, TD);
    k5_nms<<<1, 1024, 0, stream>>>(boxes4, scores, mask, TB, TD, vbp, out);
}